// Round 7
// baseline (1901.142 us; speedup 1.0000x reference)
//
#include <hip/hip_runtime.h>
#include <math.h>

#define S_ 512
#define B_ 64
#define C_ 1024
#define T_ 128
#define V_ 10
#define K_ 128
#define NCH 4
#define LN_EPS 1e-5f

// ---------- Phase 1a: per (t,b): softmax(values@Wd.T+bd), sigmoid(values@Wr[1]+br[1])
__global__ __launch_bounds__(256) void k_dirs(const float* __restrict__ values,
                                              const float* __restrict__ Wd,
                                              const float* __restrict__ bd,
                                              const float* __restrict__ Wr,
                                              const float* __restrict__ br,
                                              float* __restrict__ dtr) {
    int wid  = (blockIdx.x << 2) + (threadIdx.x >> 6);   // 0..32767 = t*64+b
    int lane = threadIdx.x & 63;
    const float4* v4  = (const float4*)(values + (size_t)wid * C_);
    const float4* wd4 = (const float4*)Wd;
    const float4* wr4 = (const float4*)Wr;
    float a0 = 0.f, a1 = 0.f, a2 = 0.f, a3 = 0.f;
#pragma unroll
    for (int k = 0; k < 4; k++) {
        int i = (k << 6) + lane;
        float4 v  = v4[i];
        float4 w0 = wd4[i];
        float4 w1 = wd4[256 + i];
        float4 w2 = wd4[512 + i];
        float4 w3 = wr4[256 + i];          // Wr row 1
        a0 = fmaf(v.x, w0.x, fmaf(v.y, w0.y, fmaf(v.z, w0.z, fmaf(v.w, w0.w, a0))));
        a1 = fmaf(v.x, w1.x, fmaf(v.y, w1.y, fmaf(v.z, w1.z, fmaf(v.w, w1.w, a1))));
        a2 = fmaf(v.x, w2.x, fmaf(v.y, w2.y, fmaf(v.z, w2.z, fmaf(v.w, w2.w, a2))));
        a3 = fmaf(v.x, w3.x, fmaf(v.y, w3.y, fmaf(v.z, w3.z, fmaf(v.w, w3.w, a3))));
    }
#pragma unroll
    for (int m = 1; m < 64; m <<= 1) {
        a0 += __shfl_xor(a0, m, 64);
        a1 += __shfl_xor(a1, m, 64);
        a2 += __shfl_xor(a2, m, 64);
        a3 += __shfl_xor(a3, m, 64);
    }
    if (lane == 0) {
        float l0 = a0 + bd[0], l1 = a1 + bd[1], l2 = a2 + bd[2];
        float mx = fmaxf(fmaxf(l0, l1), l2);
        float e0 = __expf(l0 - mx), e1 = __expf(l1 - mx), e2 = __expf(l2 - mx);
        float inv = 1.f / (e0 + e1 + e2);
        float r = 1.f / (1.f + __expf(-(a3 + br[1])));
        ((float4*)dtr)[wid] = make_float4(e0 * inv, e1 * inv, e2 * inv, r);
    }
}

// ---------- Phase 1b: evolve pos; store pos_t (pre-update), layout [b][t][l].
__global__ __launch_bounds__(64) void k_pos(const float* __restrict__ dtr,
                                            float* __restrict__ pos_all) {
    int b = blockIdx.x;
    int lane = threadIdx.x;
    const float4* dtr4 = (const float4*)dtr;
    float4 dreg[8];
#pragma unroll
    for (int k = 0; k < 8; k++)
        dreg[k] = dtr4[(((size_t)(k << 6) + lane) << 6) + b];   // t = k*64+lane
    float p0 = (lane == 0) ? 1.f : 0.f;
    float p1 = 0.f;
    float* outp = pos_all + (size_t)b * (S_ * T_) + lane;
    int up = (lane + 1) & 63, dw = (lane + 63) & 63;
#pragma unroll
    for (int k = 0; k < 8; k++) {
#pragma unroll 4
        for (int tt = 0; tt < 64; tt++) {
            int t = (k << 6) + tt;
            float d0 = __shfl(dreg[k].x, tt, 64);
            float d1 = __shfl(dreg[k].y, tt, 64);
            float d2 = __shfl(dreg[k].z, tt, 64);
            outp[(size_t)t * T_]      = p0;   // pos_t before update
            outp[(size_t)t * T_ + 64] = p1;
            float s0n = __shfl(p0, up, 64), s1n = __shfl(p1, up, 64);
            float s0p = __shfl(p0, dw, 64), s1p = __shfl(p1, dw, 64);
            float up0 = (lane == 63) ? s1n : s0n;
            float dn0 = (lane == 0)  ? s1p : s0p;
            float up1 = (lane == 63) ? s0n : s1n;
            float dn1 = (lane == 0)  ? s0p : s1p;
            p0 = fmaf(up0, d0, fmaf(p0, d1, dn0 * d2));
            p1 = fmaf(up1, d0, fmaf(p1, d1, dn1 * d2));
        }
    }
}

// ---------- Phase 1c: Gram matrices G[b][ch][j][i] = <pos_{t0+j}, pos_{t0+i}>
// (zeroed for i<=j) and w-vectors wbuf[b][ch][i] = rw_{t0+i}.
__global__ __launch_bounds__(256, 2) void k_gram(const float* __restrict__ pos_all,
                                                 const float* __restrict__ dtr,
                                                 float* __restrict__ G_all,
                                                 float* __restrict__ wbuf) {
    __shared__ float Pg[K_ * T_];        // [l][i], 64 KB
    int bc = blockIdx.x;                 // b*4 + ch
    int b = bc >> 2, ch = bc & 3;
    int t0 = ch << 7;
    int tid = threadIdx.x, lane = tid & 63, w = tid >> 6;
    const float* pb = pos_all + (size_t)b * (S_ * T_);
    // stage P^T: wave w -> rows l=32w..32w+31; lane -> i (uncoalesced global, L2-hot;
    // LDS writes lane-consecutive -> conflict-free)
    for (int r = 0; r < 32; r++) {
        int l = (w << 5) + r;
        Pg[(l << 7) + lane]      = pb[(size_t)(t0 + lane) * T_ + l];
        Pg[(l << 7) + 64 + lane] = pb[(size_t)(t0 + 64 + lane) * T_ + l];
    }
    if (tid < K_)
        wbuf[(size_t)bc * K_ + tid] = dtr[((size_t)(t0 + tid) * B_ + b) * 4 + 3];
    __syncthreads();
    // wave w owns j = w + 4*jj; lanes own i = lane, lane+64. l outer for LDS reuse.
    float acc[64];
#pragma unroll
    for (int k = 0; k < 64; k++) acc[k] = 0.f;
    for (int l = 0; l < T_; l++) {
        float pi0 = Pg[(l << 7) + lane];
        float pi1 = Pg[(l << 7) + 64 + lane];
#pragma unroll
        for (int jj = 0; jj < 32; jj++) {
            float pj = Pg[(l << 7) + w + (jj << 2)];     // broadcast
            acc[2 * jj]     = fmaf(pj, pi0, acc[2 * jj]);
            acc[2 * jj + 1] = fmaf(pj, pi1, acc[2 * jj + 1]);
        }
    }
    float* Gb = G_all + ((size_t)bc << 14);
#pragma unroll
    for (int jj = 0; jj < 32; jj++) {
        int j = w + (jj << 2);
        Gb[(j << 7) + lane]      = (lane > j)      ? acc[2 * jj]     : 0.f;
        Gb[(j << 7) + 64 + lane] = (64 + lane > j) ? acc[2 * jj + 1] : 0.f;
    }
}

// ---------- Phase 2: one chunk of 128 steps, Gram-reformulated.
// thread = (b,c). x[i] = v_i - a_i -> triangular solve -> delta_i; tape update.
// P in LDS [l][i]; ALL P reads are wave-uniform float4 broadcasts (conflict-free).
// G/w reads wave-uniform -> scalar loads.
__global__ __launch_bounds__(256, 2) void k_chunk(const float* __restrict__ values,
                                                  const float* __restrict__ pos_all,
                                                  const float* __restrict__ G_all,
                                                  const float* __restrict__ wbuf,
                                                  float* __restrict__ tape,
                                                  int ck, int has_t0) {
    __shared__ float Pc[K_ * T_];        // [l][i], 64 KB
    int b = blockIdx.x >> 2;
    int tid = threadIdx.x, lane = tid & 63, w = tid >> 6;
    int c = ((blockIdx.x & 3) << 8) + tid;
    int t0 = ck << 7;
    const float* pb = pos_all + (size_t)b * (S_ * T_);
    for (int r = 0; r < 32; r++) {
        int l = (w << 5) + r;
        Pc[(l << 7) + lane]      = pb[(size_t)(t0 + lane) * T_ + l];
        Pc[(l << 7) + 64 + lane] = pb[(size_t)(t0 + 64 + lane) * T_ + l];
    }
    __syncthreads();

    float x[K_];
    const float* vp = values + (size_t)b * C_ + c;
#pragma unroll
    for (int i = 0; i < K_; i++)
        x[i] = vp[(size_t)(t0 + i) * (B_ * C_)];

    float* tp = tape + (size_t)b * C_ + c;   // + l*B_*C_
    if (has_t0) {
        // x_i -= sum_l P[l][i] * T0[l][c]   (128 indep fma per 1 coalesced load)
#pragma unroll 2
        for (int l = 0; l < T_; l++) {
            float t0v = tp[(size_t)l * (B_ * C_)];
            const float4* pr = (const float4*)(Pc + (l << 7));
#pragma unroll
            for (int k = 0; k < 32; k++) {
                float4 p = pr[k];
                x[4 * k]     = fmaf(-p.x, t0v, x[4 * k]);
                x[4 * k + 1] = fmaf(-p.y, t0v, x[4 * k + 1]);
                x[4 * k + 2] = fmaf(-p.z, t0v, x[4 * k + 2]);
                x[4 * k + 3] = fmaf(-p.w, t0v, x[4 * k + 3]);
            }
        }
    }

    // triangular solve: x_j <- w_j * x_j; then x_i -= G[j][i] * x_j for i>j.
    // i-start rounded down to a multiple of 4: touched i<=j entries have G==0.
    const float* Gb = G_all + ((size_t)(b * NCH + ck) << 14);
    const float* wb = wbuf + (size_t)(b * NCH + ck) * K_;
#pragma unroll
    for (int j = 0; j < K_; j++) {
        float xj = x[j] * wb[j];
        x[j] = xj;
        const float* gr = Gb + (j << 7);
#pragma unroll
        for (int i = (j + 1) & ~3; i < K_; i += 4) {
            x[i]     = fmaf(-gr[i],     xj, x[i]);
            x[i + 1] = fmaf(-gr[i + 1], xj, x[i + 1]);
            x[i + 2] = fmaf(-gr[i + 2], xj, x[i + 2]);
            x[i + 3] = fmaf(-gr[i + 3], xj, x[i + 3]);
        }
    }

    // update: T1[l][c] = (has_t0 ? T0[l][c] : 0) + sum_i P[l][i] * delta_i
    if (has_t0) {
#pragma unroll 2
        for (int l = 0; l < T_; l++) {
            float a0 = tp[(size_t)l * (B_ * C_)], a1 = 0.f, a2 = 0.f, a3 = 0.f;
            const float4* pr = (const float4*)(Pc + (l << 7));
#pragma unroll
            for (int k = 0; k < 32; k++) {
                float4 p = pr[k];
                a0 = fmaf(p.x, x[4 * k],     a0);
                a1 = fmaf(p.y, x[4 * k + 1], a1);
                a2 = fmaf(p.z, x[4 * k + 2], a2);
                a3 = fmaf(p.w, x[4 * k + 3], a3);
            }
            tp[(size_t)l * (B_ * C_)] = (a0 + a1) + (a2 + a3);
        }
    } else {
#pragma unroll 2
        for (int l = 0; l < T_; l++) {
            float a0 = 0.f, a1 = 0.f, a2 = 0.f, a3 = 0.f;
            const float4* pr = (const float4*)(Pc + (l << 7));
#pragma unroll
            for (int k = 0; k < 32; k++) {
                float4 p = pr[k];
                a0 = fmaf(p.x, x[4 * k],     a0);
                a1 = fmaf(p.y, x[4 * k + 1], a1);
                a2 = fmaf(p.z, x[4 * k + 2], a2);
                a3 = fmaf(p.w, x[4 * k + 3], a3);
            }
            tp[(size_t)l * (B_ * C_)] = (a0 + a1) + (a2 + a3);
        }
    }
}

// ---------- Phase 3: LayerNorm over C + projection to V=10. one wave per (l,b).
__global__ __launch_bounds__(256) void k_out(const float* __restrict__ tape,
                                             const float* __restrict__ ln_g,
                                             const float* __restrict__ ln_b,
                                             const float* __restrict__ Wo,
                                             const float* __restrict__ bo,
                                             float* __restrict__ out) {
    int wid  = (blockIdx.x << 2) + (threadIdx.x >> 6);   // 0..8191 = l*64+b
    int lane = threadIdx.x & 63;
    const float* tr = tape + (size_t)wid * C_;
    float x[16];
    float s = 0.f, s2 = 0.f;
#pragma unroll
    for (int k = 0; k < 16; k++) {
        x[k] = tr[(k << 6) + lane];
        s += x[k];
        s2 = fmaf(x[k], x[k], s2);
    }
#pragma unroll
    for (int m = 1; m < 64; m <<= 1) {
        s  += __shfl_xor(s,  m, 64);
        s2 += __shfl_xor(s2, m, 64);
    }
    float mu = s * (1.f / C_);
    float var = s2 * (1.f / C_) - mu * mu;
    float rstd = rsqrtf(var + LN_EPS);
    float acc[V_];
#pragma unroll
    for (int v = 0; v < V_; v++) acc[v] = 0.f;
#pragma unroll
    for (int k = 0; k < 16; k++) {
        int cc = (k << 6) + lane;
        float h = fmaf((x[k] - mu) * rstd, ln_g[cc], ln_b[cc]);
#pragma unroll
        for (int v = 0; v < V_; v++) acc[v] = fmaf(h, Wo[v * C_ + cc], acc[v]);
    }
#pragma unroll
    for (int v = 0; v < V_; v++) {
#pragma unroll
        for (int m = 1; m < 64; m <<= 1) acc[v] += __shfl_xor(acc[v], m, 64);
    }
    if (lane == 0) {
#pragma unroll
        for (int v = 0; v < V_; v++) out[(size_t)wid * V_ + v] = acc[v] + bo[v];
    }
}

extern "C" void kernel_launch(void* const* d_in, const int* in_sizes, int n_in,
                              void* d_out, int out_size, void* d_ws, size_t ws_size,
                              hipStream_t stream) {
    const float* values = (const float*)d_in[0];
    const float* Wd     = (const float*)d_in[1];
    const float* bd     = (const float*)d_in[2];
    const float* Wr     = (const float*)d_in[3];
    const float* br     = (const float*)d_in[4];
    const float* ln_g   = (const float*)d_in[5];
    const float* ln_b   = (const float*)d_in[6];
    const float* Wo     = (const float*)d_in[7];
    const float* bo     = (const float*)d_in[8];
    float* out = (float*)d_out;

    // workspace (floats): dtr [512*64*4] | pos_all [64][512][128] |
    //                     G_all [256][128][128] | wbuf [256][128] | tape [128][64][1024]
    float* dtr     = (float*)d_ws;
    float* pos_all = dtr + (size_t)S_ * B_ * 4;
    float* G_all   = pos_all + (size_t)B_ * S_ * T_;
    float* wbuf    = G_all + (size_t)B_ * NCH * K_ * K_;
    float* tape    = wbuf + (size_t)B_ * NCH * K_;

    k_dirs<<<dim3((S_ * B_) / 4), dim3(256), 0, stream>>>(values, Wd, bd, Wr, br, dtr);
    k_pos <<<dim3(B_),            dim3(64),  0, stream>>>(dtr, pos_all);
    k_gram<<<dim3(B_ * NCH),      dim3(256), 0, stream>>>(pos_all, dtr, G_all, wbuf);
    for (int ck = 0; ck < NCH; ck++)
        k_chunk<<<dim3(B_ * 4), dim3(256), 0, stream>>>(values, pos_all, G_all, wbuf,
                                                        tape, ck, ck > 0 ? 1 : 0);
    k_out<<<dim3((T_ * B_) / 4), dim3(256), 0, stream>>>(tape, ln_g, ln_b, Wo, bo, out);
}